// Round 2
// baseline (1038.741 us; speedup 1.0000x reference)
//
#include <hip/hip_runtime.h>

typedef __attribute__((ext_vector_type(8))) _Float16 half8;
typedef __attribute__((ext_vector_type(4))) float floatx4;

#define NN    10000
#define EE    640000
#define DD    128
#define EDD   64
#define HH    8
#define OUTD  128

__device__ __forceinline__ float fast_rcp(float x) { return __builtin_amdgcn_rcpf(x); }

// load 8 consecutive floats, convert to fp16 fragment
__device__ __forceinline__ half8 cvt8h(const float* __restrict__ p) {
    const floatx4 a = *(const floatx4*)(const void*)p;
    const floatx4 b = *(const floatx4*)(const void*)(p + 4);
    half8 r;
    r[0] = (_Float16)a[0]; r[1] = (_Float16)a[1];
    r[2] = (_Float16)a[2]; r[3] = (_Float16)a[3];
    r[4] = (_Float16)b[0]; r[5] = (_Float16)b[1];
    r[6] = (_Float16)b[2]; r[7] = (_Float16)b[3];
    return r;
}

// edge-index format check: int64 data read as int32 has zero hi-words
__device__ __forceinline__ int idx_is64(const int* __restrict__ eidx) {
    return ((eidx[1] | eidx[3] | eidx[5] | eidx[7]) == 0) ? 1 : 0;
}

// ---------------------------------------------------------------------------
// K1: node projections q,k and MLP v (fp32 in -> fp16 internal); zero sf.
// One wave per 16-node tile (625 tiles exactly).
// ---------------------------------------------------------------------------
__global__ void __launch_bounds__(64) k_node(
    const float* __restrict__ h,
    const float* __restrict__ Wq, const float* __restrict__ bq,
    const float* __restrict__ Wk, const float* __restrict__ bk,
    const float* __restrict__ W1, const float* __restrict__ b1,
    const float* __restrict__ W2, const float* __restrict__ b2,
    _Float16* __restrict__ qb, _Float16* __restrict__ kb,
    _Float16* __restrict__ vb, float* __restrict__ sf)
{
    __shared__ _Float16 L[16 * 136];
    const int lane = threadIdx.x;
    const int tile = blockIdx.x;
    const int c16 = lane & 15, q4 = lane >> 4;
    const int m0 = tile * 16;

    // zero sf: 625*64 threads cover 80000 floats
    const int tid = tile * 64 + lane;
    sf[tid] = 0.0f;
    sf[tid + 40000] = 0.0f;

    // A-frags from h rows: A[m=c16][k=q4*8+j], k-steps 0,32,64,96
    const float* hrow = h + (m0 + c16) * DD + q4 * 8;
    half8 af[4];
    af[0] = cvt8h(hrow + 0);
    af[1] = cvt8h(hrow + 32);
    af[2] = cvt8h(hrow + 64);
    af[3] = cvt8h(hrow + 96);

    // q and k projections
    for (int w = 0; w < 2; ++w) {
        const float* W  = w ? Wk : Wq;
        const float* Bv = w ? bk : bq;
        _Float16* dst   = w ? kb : qb;
        for (int nt = 0; nt < 8; ++nt) {
            const int col = nt * 16 + c16;
            const float bias = Bv[col];
            floatx4 acc = {bias, bias, bias, bias};
            const float* wr = W + col * DD + q4 * 8;
            for (int s = 0; s < 4; ++s)
                acc = __builtin_amdgcn_mfma_f32_16x16x32_f16(
                    af[s], cvt8h(wr + s * 32), acc, 0, 0, 0);
            for (int r = 0; r < 4; ++r)
                dst[(m0 + q4 * 4 + r) * DD + col] = (_Float16)acc[r];
        }
    }

    // MLP layer 1 + silu -> LDS (fp16)
    for (int nt = 0; nt < 8; ++nt) {
        const int col = nt * 16 + c16;
        const float bias = b1[col];
        floatx4 acc = {bias, bias, bias, bias};
        const float* wr = W1 + col * DD + q4 * 8;
        for (int s = 0; s < 4; ++s)
            acc = __builtin_amdgcn_mfma_f32_16x16x32_f16(
                af[s], cvt8h(wr + s * 32), acc, 0, 0, 0);
        for (int r = 0; r < 4; ++r) {
            const float x = acc[r];
            L[(q4 * 4 + r) * 136 + col] = (_Float16)(x * fast_rcp(1.0f + __expf(-x)));
        }
    }
    __syncthreads();

    // MLP layer 2 -> vb
    half8 af2[4];
    const _Float16* l2 = L + c16 * 136 + q4 * 8;
    for (int s = 0; s < 4; ++s)
        af2[s] = *(const half8*)(const void*)(l2 + s * 32);
    for (int nt = 0; nt < 8; ++nt) {
        const int col = nt * 16 + c16;
        const float bias = b2[col];
        floatx4 acc = {bias, bias, bias, bias};
        const float* wr = W2 + col * DD + q4 * 8;
        for (int s = 0; s < 4; ++s)
            acc = __builtin_amdgcn_mfma_f32_16x16x32_f16(
                af2[s], cvt8h(wr + s * 32), acc, 0, 0, 0);
        for (int r = 0; r < 4; ++r)
            vb[(m0 + q4 * 4 + r) * DD + col] = (_Float16)acc[r];
    }
}

// ---------------------------------------------------------------------------
// K2: re = silu(t@Wre.T+bre) fused; a = sum_head(q_i*k_j*re); ex=exp(a)->exf;
// atomicAdd into sf[n_i*H+head]. One wave per 16-edge tile; 40000 tiles.
// ---------------------------------------------------------------------------
__global__ void __launch_bounds__(256) k_logits(
    const float* __restrict__ t, const int* __restrict__ eidx,
    const float* __restrict__ Wre, const float* __restrict__ bre,
    const _Float16* __restrict__ qb, const _Float16* __restrict__ kb,
    float* __restrict__ exf, float* __restrict__ sf)
{
    const int wave = threadIdx.x >> 6;
    const int lane = threadIdx.x & 63;
    const int c16 = lane & 15, q4 = lane >> 4;
    const int tile = blockIdx.x * 4 + wave;
    const int m0 = tile * 16;

    const int is64 = idx_is64(eidx);

    // A-frags from t rows (K=64 -> 2 k-steps)
    const float* trow = t + (m0 + c16) * EDD + q4 * 8;
    const half8 a0 = cvt8h(trow);
    const half8 a1 = cvt8h(trow + 32);

    int e_r[4], ni_r[4], nj_r[4];
    for (int r = 0; r < 4; ++r) {
        const int e = m0 + q4 * 4 + r;
        e_r[r] = e;
        if (is64) { nj_r[r] = eidx[2 * e];      ni_r[r] = eidx[2 * EE + 2 * e]; }
        else      { nj_r[r] = eidx[e];          ni_r[r] = eidx[EE + e]; }
    }

    for (int nt = 0; nt < 8; ++nt) {   // nt == head
        const int col = nt * 16 + c16;
        const float bias = bre[col];
        floatx4 acc = {bias, bias, bias, bias};
        const float* wr = Wre + col * EDD + q4 * 8;
        acc = __builtin_amdgcn_mfma_f32_16x16x32_f16(a0, cvt8h(wr), acc, 0, 0, 0);
        acc = __builtin_amdgcn_mfma_f32_16x16x32_f16(a1, cvt8h(wr + 32), acc, 0, 0, 0);

        float part[4];
        for (int r = 0; r < 4; ++r) {
            const float x = acc[r];
            const float re = x * fast_rcp(1.0f + __expf(-x));   // silu
            const float qv = (float)qb[ni_r[r] * DD + col];
            const float kv = (float)kb[nj_r[r] * DD + col];
            part[r] = re * qv * kv;
        }
        // reduce over the 16 lanes of this quad (lane bits 0..3)
        for (int m = 1; m < 16; m <<= 1) {
            part[0] += __shfl_xor(part[0], m, 64);
            part[1] += __shfl_xor(part[1], m, 64);
            part[2] += __shfl_xor(part[2], m, 64);
            part[3] += __shfl_xor(part[3], m, 64);
        }
        if (c16 < 4) {
            const int r = c16;
            const float ex = __expf(part[r]);
            exf[e_r[r] * HH + nt] = ex;
            atomicAdd(&sf[ni_r[r] * HH + nt], ex);
        }
    }
}

// ---------------------------------------------------------------------------
// K3: out[e,:] = ((ex/s)*0.25 ⊙ v[n_j]) @ Wc.T + bc, fp32 out.
// One wave per 16-edge tile; LDS-transpose epilogue for coalesced stores.
// ---------------------------------------------------------------------------
__global__ void __launch_bounds__(256) k_out(
    const int* __restrict__ eidx, const float* __restrict__ exf,
    const float* __restrict__ sf, const _Float16* __restrict__ vb,
    const float* __restrict__ Wc, const float* __restrict__ bc,
    float* __restrict__ outp)
{
    __shared__ float Lf[4][16 * 132];
    const int wave = threadIdx.x >> 6;
    const int lane = threadIdx.x & 63;
    const int c16 = lane & 15, q4 = lane >> 4;
    const int tile = blockIdx.x * 4 + wave;
    const int m0 = tile * 16;

    const int is64 = idx_is64(eidx);

    const int e_a = m0 + c16;         // my A-frag row's edge
    int nj, ni;
    if (is64) { nj = eidx[2 * e_a]; ni = eidx[2 * EE + 2 * e_a]; }
    else      { nj = eidx[e_a];     ni = eidx[EE + e_a]; }

    // A-frags: y[c] = (ex/(s+eps))*0.25 * v[nj][c], c = s*32 + q4*8 + j
    half8 af[4];
    for (int s = 0; s < 4; ++s) {
        const int h0 = s * 2 + (q4 >> 1);            // head, uniform per (s,q4)
        const float exv = exf[e_a * HH + h0];
        const float sv = sf[ni * HH + h0];
        const float asc = exv * fast_rcp(sv + 1e-16f) * 0.25f;
        const half8 v8 = *(const half8*)(const void*)(vb + nj * DD + s * 32 + q4 * 8);
        half8 y;
        for (int j = 0; j < 8; ++j)
            y[j] = (_Float16)((float)v8[j] * asc);
        af[s] = y;
    }

    floatx4 acc[8];
    for (int nt = 0; nt < 8; ++nt) {
        const int col = nt * 16 + c16;
        const float bias = bc[col];
        acc[nt] = (floatx4){bias, bias, bias, bias};
        const float* wr = Wc + col * DD + q4 * 8;
        for (int s = 0; s < 4; ++s)
            acc[nt] = __builtin_amdgcn_mfma_f32_16x16x32_f16(
                af[s], cvt8h(wr + s * 32), acc[nt], 0, 0, 0);
    }

    // stage to LDS (row = edge-in-tile, col = out feature), coalesced fp32 store
    float* Lw = Lf[wave];
    for (int nt = 0; nt < 8; ++nt)
        for (int r = 0; r < 4; ++r)
            Lw[(q4 * 4 + r) * 132 + nt * 16 + c16] = acc[nt][r];
    __syncthreads();

    float* ob = outp + (size_t)m0 * OUTD;   // 16 rows x 512B contiguous
    for (int tt = 0; tt < 8; ++tt) {
        const int idx = tt * 64 + lane;      // float4-chunk id, 0..511
        const int row = idx >> 5;            // 32 chunks per row
        const int c4 = (idx & 31) * 4;
        const floatx4 val = *(const floatx4*)(const void*)&Lw[row * 132 + c4];
        *(floatx4*)(void*)(ob + row * OUTD + c4) = val;
    }
}

// ---------------------------------------------------------------------------
extern "C" void kernel_launch(void* const* d_in, const int* in_sizes, int n_in,
                              void* d_out, int out_size, void* d_ws, size_t ws_size,
                              hipStream_t stream) {
    (void)in_sizes; (void)n_in; (void)out_size; (void)ws_size;
    const float* h   = (const float*)d_in[0];
    const float* t   = (const float*)d_in[1];
    const int*   eidx= (const int*)d_in[2];
    const float* Wq  = (const float*)d_in[3];
    const float* bq  = (const float*)d_in[4];
    const float* Wk  = (const float*)d_in[5];
    const float* bk  = (const float*)d_in[6];
    const float* W1  = (const float*)d_in[7];
    const float* b1  = (const float*)d_in[8];
    const float* W2  = (const float*)d_in[9];
    const float* b2  = (const float*)d_in[10];
    const float* Wre = (const float*)d_in[11];
    const float* bre = (const float*)d_in[12];
    const float* Wc  = (const float*)d_in[13];
    const float* bc  = (const float*)d_in[14];
    float* out = (float*)d_out;

    char* ws = (char*)d_ws;
    _Float16* qb = (_Float16*)(ws);                // N*128 fp16 = 2,560,000 B
    _Float16* kb = (_Float16*)(ws + 2560000);
    _Float16* vb = (_Float16*)(ws + 5120000);
    float*    exf= (float*)   (ws + 7680000);      // E*8 f32 = 20,480,000 B
    float*    sf = (float*)   (ws + 28160000);     // N*8 f32 = 320,000 B

    k_node<<<dim3(625), dim3(64), 0, stream>>>(h, Wq, bq, Wk, bk, W1, b1, W2, b2,
                                               qb, kb, vb, sf);
    k_logits<<<dim3(10000), dim3(256), 0, stream>>>(t, eidx, Wre, bre, qb, kb, exf, sf);
    k_out<<<dim3(10000), dim3(256), 0, stream>>>(eidx, exf, sf, vb, Wc, bc, out);
}